// Round 2
// 417.221 us; speedup vs baseline: 1.0163x; 1.0163x over previous
//
#include <hip/hip_runtime.h>

// ---------------------------------------------------------------------------
// Kernel A: segment boundaries in SORTED domain_ids.
// starts[d]=-1 (memset 0xFF) means empty domain.
// ---------------------------------------------------------------------------
__global__ void bounds_kernel(const int* __restrict__ dids,
                              int* __restrict__ starts,
                              int* __restrict__ ends, int E) {
    int e = blockIdx.x * blockDim.x + threadIdx.x;
    if (e >= E) return;
    int d = dids[e];
    if (e == 0) {
        starts[d] = 0;
    } else {
        int dp = dids[e - 1];
        if (d != dp) {
            starts[d] = e;
            ends[dp]  = e;
        }
    }
    if (e == E - 1) ends[d] = E;
}

// ---------------------------------------------------------------------------
// Kernel B v4: gather + segment-sum, one wave per domain.
// 16-lane groups gather a whole atom row as float4 (16 B/lane), 4 entries
// concurrently per wave-load phase. One wave-load moves 1 KB instead of
// 256 B -> 4x fewer VMEM instructions and 4x less TA address-processing per
// byte. Indices for a 16-entry batch are fetched once (single 64 B vector
// load, lanes duplicated 4x) and distributed to phases via __shfl. Dynamic
// phase count for the tail batch kills most of v3's 55% clamped-load
// overshoot. Final cross-group reduce: shfl_xor over lane bits 4,5; lanes
// 0-15 store the 256 B output row.
// ---------------------------------------------------------------------------
__global__ void seg_sum_kernel(const float* __restrict__ feat,
                               const int* __restrict__ aidx,
                               const int* __restrict__ starts,
                               const int* __restrict__ ends,
                               float* __restrict__ T, int M) {
    int wid  = (int)(((size_t)blockIdx.x * blockDim.x + threadIdx.x) >> 6);
    if (wid >= M) return;
    int lane = threadIdx.x & 63;
    int g    = lane >> 4;          // entry-phase group 0..3
    int l16  = lane & 15;          // float4 chunk within the 64-ch row
    int coff = l16 * 4;            // channel offset

    int s = starts[wid];
    int e = ends[wid];

    float4 acc = make_float4(0.f, 0.f, 0.f, 0.f);
    if (s >= 0) {
        int last = e - 1;
        for (int base = s; base < e; base += 16) {
            int rem = e - base;            // uniform, >= 1
            int ti  = base + l16;
            // 16 distinct dwords, 4x lane-duplicated -> one coalesced request
            int idxv = aidx[ti <= last ? ti : last];
            if (rem >= 16) {
                // full batch: all 16 entries valid, no predication needed
#pragma unroll
                for (int p = 0; p < 4; ++p) {
                    int row = __shfl(idxv, p * 4 + g, 64);
                    const float4 v =
                        *(const float4*)(feat + (size_t)row * 64 + coff);
                    acc.x += v.x; acc.y += v.y; acc.z += v.z; acc.w += v.w;
                }
            } else {
                int nph = (rem + 3) >> 2;  // uniform phase count
                for (int p = 0; p < nph; ++p) {
                    int t   = base + p * 4 + g;
                    int row = __shfl(idxv, p * 4 + g, 64);
                    const float4 v =
                        *(const float4*)(feat + (size_t)row * 64 + coff);
                    float w = (t <= last) ? 1.f : 0.f;
                    acc.x = fmaf(v.x, w, acc.x);
                    acc.y = fmaf(v.y, w, acc.y);
                    acc.z = fmaf(v.z, w, acc.z);
                    acc.w = fmaf(v.w, w, acc.w);
                }
            }
        }
        // fold the 4 group partials: butterfly over lane bits 4 and 5
        acc.x += __shfl_xor(acc.x, 16, 64);
        acc.y += __shfl_xor(acc.y, 16, 64);
        acc.z += __shfl_xor(acc.z, 16, 64);
        acc.w += __shfl_xor(acc.w, 16, 64);
        acc.x += __shfl_xor(acc.x, 32, 64);
        acc.y += __shfl_xor(acc.y, 32, 64);
        acc.z += __shfl_xor(acc.z, 32, 64);
        acc.w += __shfl_xor(acc.w, 32, 64);
    }
    if (g == 0)
        *(float4*)(T + (size_t)wid * 64 + coff) = acc;
}

// ---------------------------------------------------------------------------
// Proj v4: out = T @ W + b as an LDS-tiled register-blocked GEMM.
// Block 256 threads handles a 64-row x 128-col tile.
//   lds_w[k][c]          : 64x128 f32 = 32 KB (W's native layout, float4 copy)
//   lds_t[k][row]        : T tile TRANSPOSED, stride 68 floats (16B-aligned
//                          b128 reads, bank spread)
// Thread (tid) owns rows r0..r0+7 (r0=(tid>>5)*8) x cols c0..c0+3
// (c0=(tid&31)*4): per k-step 2+1 ds_read_b128 + 32 v_fma_f32, acc in 32
// VGPRs. FMA floor = 2.05e9 FMA / (256 CU * 128 lanes/cy) = 26 us.
// Stores: 32 contiguous lanes cover a full 512 B output row -> coalesced.
// ---------------------------------------------------------------------------
#define TM 64
__global__ void __launch_bounds__(256)
proj_kernel(const float* __restrict__ T,
            const float* __restrict__ W,
            const float* __restrict__ bias,
            float* __restrict__ out, int M) {
    __shared__ float lds_w[64][128];
    __shared__ float lds_t[64][TM + 4];   // stride 68 floats = 272 B (16B mult)

    int tid  = threadIdx.x;
    int row0 = blockIdx.x * TM;

    // Stage W: 8192 floats = 2048 float4, 8 per thread, coalesced.
#pragma unroll
    for (int i = 0; i < 8; ++i) {
        int idx = tid + i * 256;          // 0..2047
        int k   = idx >> 5;
        int ch  = idx & 31;
        float4 wv = ((const float4*)W)[idx];
        *(float4*)&lds_w[k][ch * 4] = wv;
    }
    // Stage T transposed: 64 rows x 16 float4 chunks, 4 per thread.
#pragma unroll
    for (int i = 0; i < 4; ++i) {
        int idx = tid + i * 256;          // 0..1023
        int r   = idx >> 4;
        int ch  = idx & 15;
        long gr = row0 + r;
        if (gr > (long)M - 1) gr = M - 1; // clamp: valid mem, stores guarded
        float4 tv = ((const float4*)(T + gr * 64))[ch];
        lds_t[ch * 4 + 0][r] = tv.x;
        lds_t[ch * 4 + 1][r] = tv.y;
        lds_t[ch * 4 + 2][r] = tv.z;
        lds_t[ch * 4 + 3][r] = tv.w;
    }
    __syncthreads();

    int c0 = (tid & 31) * 4;
    int r0 = (tid >> 5) * 8;

    float acc[8][4];
#pragma unroll
    for (int r = 0; r < 8; ++r)
#pragma unroll
        for (int c = 0; c < 4; ++c) acc[r][c] = 0.f;

#pragma unroll 8
    for (int k = 0; k < 64; ++k) {
        float4 ta = *(const float4*)&lds_t[k][r0];
        float4 tb = *(const float4*)&lds_t[k][r0 + 4];
        float4 wv = *(const float4*)&lds_w[k][c0];
        float t[8] = {ta.x, ta.y, ta.z, ta.w, tb.x, tb.y, tb.z, tb.w};
        float w[4] = {wv.x, wv.y, wv.z, wv.w};
#pragma unroll
        for (int r = 0; r < 8; ++r)
#pragma unroll
            for (int c = 0; c < 4; ++c)
                acc[r][c] = fmaf(t[r], w[c], acc[r][c]);
    }

    float4 bv = *(const float4*)&bias[c0];
#pragma unroll
    for (int r = 0; r < 8; ++r) {
        long row = row0 + r0 + r;
        if (row < M) {
            float4 o;
            o.x = acc[r][0] + bv.x;
            o.y = acc[r][1] + bv.y;
            o.z = acc[r][2] + bv.z;
            o.w = acc[r][3] + bv.w;
            *(float4*)&out[row * 128 + c0] = o;
        }
    }
}

extern "C" void kernel_launch(void* const* d_in, const int* in_sizes, int n_in,
                              void* d_out, int out_size, void* d_ws, size_t ws_size,
                              hipStream_t stream) {
    const float* feat = (const float*)d_in[0];   // [N_ATOMS, 64] f32
    const int*   aidx = (const int*)d_in[1];     // [E] int
    const int*   dids = (const int*)d_in[2];     // [E] int (sorted)
    const float* W    = (const float*)d_in[4];   // [64, 128] f32
    const float* bias = (const float*)d_in[5];   // [128] f32
    float*       out  = (float*)d_out;           // [M, 128] f32

    int E = in_sizes[1];
    int M = out_size / 128;

    float* T = (float*)d_ws;                     // [M, 64] f32 = 64 MB
    size_t tbytes = (size_t)M * 64 * sizeof(float);
    size_t bbytes = 2 * (size_t)M * sizeof(int);

    int* starts;
    if (ws_size >= tbytes + bbytes) {
        starts = (int*)((char*)d_ws + tbytes);
    } else {
        // Stash boundaries in the tail of d_out; proj overwrites them only
        // after seg_sum consumed them (same-stream serialization).
        starts = (int*)((char*)d_out + (size_t)out_size * sizeof(float) - bbytes);
    }
    int* ends = starts + M;

    hipMemsetAsync(starts, 0xFF, bbytes, stream);

    bounds_kernel<<<(E + 255) / 256, 256, 0, stream>>>(dids, starts, ends, E);

    int waves_blocks = (int)(((size_t)M * 64 + 255) / 256);
    seg_sum_kernel<<<waves_blocks, 256, 0, stream>>>(feat, aidx, starts, ends, T, M);

    proj_kernel<<<(M + TM - 1) / TM, 256, 0, stream>>>(T, W, bias, out, M);
}